// Round 2
// baseline (138.208 us; speedup 1.0000x reference)
//
#include <hip/hip_runtime.h>

// Problem constants (fixed by the reference file).
#define DIN 4096
#define NG  4096           // NUM_GATES = DOUT/3
#define BS  4096
#define RPB 8              // rows per block
#define BT  256            // 4 waves per block
#define GG  4              // gate-groups: each block covers 1024 gates (4/thread)

typedef float v4f __attribute__((ext_vector_type(4)));

// out[b,g] = w0*x[b,(3g+1)&4095] + w1*x[b,(3g+2)&4095] + w2*x[b,(3g+3)&4095] + w3
// (w0..w3) = softmax(wgts[g,0,0..3]). Reference's signals[:, :, ::3] selects only
// row 0 of M = [1,0,0,0,0] -> out = s[...,0]; v4/v5 and rows 1..2 are dead code.
//
// R10: fix the R9 bottleneck (1 resident 1024-thread WG/CU = 51% occupancy, and
// VGPR=32 proving the compiler didn't pipeline the row loop -> per-wave
// latency-serialized iterations at 2.5 TB/s effective).
//   - 256-thread blocks, 2048 blocks -> 8 independent blocks/CU, no barriers.
//   - Explicit 2-deep software pipeline: row r+1's loads are issued before row
//     r's compute, so each wave always has >=1 row (3 KiB) in flight.
//   - Each block covers a DISJOINT contiguous 1024-gate span -> its x-window is
//     ~3 KiB with no 3x row-wrap (R9's 1024-thread block re-read the row 3x
//     through L1).
// Window loads stay 16B-aligned (12*gq floats); per-float4 &4095 handles the
// row wrap; element 12q+12 comes from the neighbor lane via shuffle (1-lane
// global read at the wave seam, prefetched with the row).
__global__ __launch_bounds__(BT, 8) void fredkin_s0_ilp(
    const float* __restrict__ x,
    const float* __restrict__ wgts,
    float* __restrict__ out)
{
    const int tid = threadIdx.x;
    const int l   = tid & 63;                    // lane
    const int gg  = blockIdx.x & (GG - 1);       // gate group 0..3
    const int rg  = blockIdx.x >> 2;             // row group 0..511
    const int gq  = (gg << 8) + tid;             // global gate-quad id 0..1023
    const int g0  = gq << 2;                     // first of this thread's 4 gates

    // Softmax of wgts[g,0,:] (row-0 at float offset 12g, 16B aligned).
    float4 wq[4];
#pragma unroll
    for (int j = 0; j < 4; ++j) {
        float4 r = *reinterpret_cast<const float4*>(wgts + (size_t)(g0 + j) * 12);
        float m  = fmaxf(fmaxf(r.x, r.y), fmaxf(r.z, r.w));
        float e0 = __expf(r.x - m);
        float e1 = __expf(r.y - m);
        float e2 = __expf(r.z - m);
        float e3 = __expf(r.w - m);
        float inv = 1.0f / (e0 + e1 + e2 + e3);
        wq[j] = make_float4(e0 * inv, e1 * inv, e2 * inv, e3 * inv);
    }

    const int brow = rg * RPB;
    const float* xb   = x   + (size_t)brow * DIN;    // block's row 0
    float*       orow = out + (size_t)brow * NG + g0;

    // Window indices (floats). Per-float4 &4095 handles the wrapping threads.
    const int lb = (12 * gq) & (DIN - 1);
    const int i1 = (lb + 4)  & (DIN - 1);
    const int i2 = (lb + 8)  & (DIN - 1);
    const int i3 = (lb + 12) & (DIN - 1);

    // Prologue: row 0 in flight.
    float4 a0, a1, a2;
    float  as;
    {
        const float* xr = xb;
        a0 = *reinterpret_cast<const float4*>(xr + lb);   // e0..e3
        a1 = *reinterpret_cast<const float4*>(xr + i1);   // e4..e7
        a2 = *reinterpret_cast<const float4*>(xr + i2);   // e8..e11
        as = (l == 63) ? xr[i3] : 0.0f;                   // seam (1 lane)
    }

#pragma unroll
    for (int r = 0; r < RPB; ++r) {
        // Prefetch row r+1 BEFORE consuming row r: loads for r+1 are newer in
        // the vmcnt FIFO, so the compiler's counted wait for row r leaves them
        // outstanding -> each wave always has a full row in flight.
        float4 b0 = {}, b1 = {}, b2 = {};
        float  bs_ = 0.0f;
        if (r + 1 < RPB) {
            const float* xn = xb + (size_t)(r + 1) * DIN;
            b0 = *reinterpret_cast<const float4*>(xn + lb);
            b1 = *reinterpret_cast<const float4*>(xn + i1);
            b2 = *reinterpret_cast<const float4*>(xn + i2);
            bs_ = (l == 63) ? xn[i3] : 0.0f;
        }

        float e12 = __shfl_down(a0.x, 1);        // e12 = next thread's e0-slot
        if (l == 63) e12 = as;                   // wave seam

        v4f o;
        o.x = fmaf(wq[0].x, a0.y, fmaf(wq[0].y, a0.z, fmaf(wq[0].z, a0.w, wq[0].w)));
        o.y = fmaf(wq[1].x, a1.x, fmaf(wq[1].y, a1.y, fmaf(wq[1].z, a1.z, wq[1].w)));
        o.z = fmaf(wq[2].x, a1.w, fmaf(wq[2].y, a2.x, fmaf(wq[2].z, a2.y, wq[2].w)));
        o.w = fmaf(wq[3].x, a2.z, fmaf(wq[3].y, a2.w, fmaf(wq[3].z, e12, wq[3].w)));
        __builtin_nontemporal_store(o, reinterpret_cast<v4f*>(orow + (size_t)r * NG));

        a0 = b0; a1 = b1; a2 = b2; as = bs_;
    }
}

extern "C" void kernel_launch(void* const* d_in, const int* in_sizes, int n_in,
                              void* d_out, int out_size, void* d_ws, size_t ws_size,
                              hipStream_t stream) {
    const float* x    = (const float*)d_in[0];   // (BS, DIN) fp32
    const float* wgts = (const float*)d_in[1];   // (NG, 3, 4) fp32
    // d_in[2] (connections) is deterministic: (3g+1+j) % DIN — computed inline.
    float* out = (float*)d_out;                  // (BS, NG) fp32

    fredkin_s0_ilp<<<dim3((BS / RPB) * GG), dim3(BT), 0, stream>>>(x, wgts, out);
}

// Round 3
// 121.102 us; speedup vs baseline: 1.1413x; 1.1413x over previous
//
#include <hip/hip_runtime.h>

// Problem constants (fixed by the reference file).
#define DIN  4096
#define NG   4096          // NUM_GATES = DOUT/3
#define BS   4096
#define R    2             // rows per block -> 2048 blocks
#define BT   512           // 8 waves
#define GPT  8             // gates per thread = NG/BT
#define PAD  64            // wrap pad (x[0..63] replicated after x[4095])
#define ROWF (DIN + PAD)   // 4160 floats per row buffer (16640 B, 16B-aligned)

// Async global->LDS DMA. LDS dest = wave-uniform base + lane*size; global src
// is per-lane. size must be a literal (4 or 16).
__device__ __forceinline__ void dma16(const float* g, float* lds) {
    __builtin_amdgcn_global_load_lds(
        (const __attribute__((address_space(1))) void*)g,
        (__attribute__((address_space(3))) void*)lds, 16, 0, 0);
}
__device__ __forceinline__ void dma4(const float* g, float* lds) {
    __builtin_amdgcn_global_load_lds(
        (const __attribute__((address_space(1))) void*)g,
        (__attribute__((address_space(3))) void*)lds, 4, 0, 0);
}

// out[b,g] = w0*x[b,(3g+1)&4095] + w1*x[b,(3g+2)&4095] + w2*x[b,(3g+3)&4095] + w3
// (w0..w3) = softmax(wgts[g,0,0..3]). Reference's signals[:, :, ::3] selects only
// row 0 of M = [1,0,0,0,0] -> out = s[...,0]; v4/v5 and rows 1..2 are dead code.
//
// R11: small self-contained blocks, one barrier, overlap via block parallelism.
//  - Post-mortems: R10 proved splitting a row's 3x reuse across blocks
//    duplicates HBM fetch cross-XCD (42->103 MB); R9 proved a lone 1024-thread
//    WG/CU with no ILP is latency-bound at 2.5 TB/s; R8 (~29 us) won via
//    DMA+LDS but was 16-wave-lockstep with 2 syncs/row.
//  - Here: block owns rows [2b,2b+2) entirely (fetch-once, reuse intra-block),
//    stages both rows with global_load_lds, ONE __syncthreads, then computes.
//    4 resident blocks/CU (LDS 33.3 KB) in different phases give the overlap.
//  - g = tid + 512k gate map: LDS reads at dword stride 3 (coprime with 32
//    banks -> conflict-free), stores perfectly coalesced, and a 64-float wrap
//    pad removes all mod-4096 corner cases (no divergent seam load).
__global__ __launch_bounds__(BT, 8) void fredkin_rows(
    const float* __restrict__ x,
    const float* __restrict__ wgts,
    float* __restrict__ out)
{
    __shared__ float L[R][ROWF];

    const int tid = threadIdx.x;
    const int w   = tid >> 6;        // wave 0..7
    const int l   = tid & 63;        // lane
    const int row0 = blockIdx.x * R;

    // --- Stage rows [row0, row0+R) into LDS (issue first, compute softmax
    // while the DMAs fly, then barrier). Per wave per row: 2 KiB = 2 dma16.
#pragma unroll
    for (int r = 0; r < R; ++r) {
        const float* xr = x + (size_t)(row0 + r) * DIN;
        float* Lr = &L[r][0];
        dma16(xr + (w << 9) + (l << 2),       Lr + (w << 9));
        dma16(xr + (w << 9) + 256 + (l << 2), Lr + (w << 9) + 256);
    }
    if (w < R) {   // wave w pads row w: L[w][4096+l] = x[row0+w, l]
        const float* xr = x + (size_t)(row0 + w) * DIN;
        dma4(xr + l, &L[w][DIN]);
    }

    // --- Softmax of wgts[g,0,:] for my GPT gates (overlaps the DMA latency).
    float4 wq[GPT];
#pragma unroll
    for (int k = 0; k < GPT; ++k) {
        const int g = tid + (k << 9);
        float4 rr = *reinterpret_cast<const float4*>(wgts + (size_t)g * 12);
        float m  = fmaxf(fmaxf(rr.x, rr.y), fmaxf(rr.z, rr.w));
        float e0 = __expf(rr.x - m);
        float e1 = __expf(rr.y - m);
        float e2 = __expf(rr.z - m);
        float e3 = __expf(rr.w - m);
        float inv = 1.0f / (e0 + e1 + e2 + e3);
        wq[k] = make_float4(e0 * inv, e1 * inv, e2 * inv, e3 * inv);
    }

    __syncthreads();   // vmcnt(0)+barrier: all waves' DMA data visible

    // --- Compute. Gate g = tid + 512k reads L[r][jb+1..jb+3], jb=(3g)&4095;
    // pad makes jb+3 <= 4098 always valid and wrap-correct.
    const int t3 = 3 * tid;
#pragma unroll
    for (int r = 0; r < R; ++r) {
        const float* Lr = &L[r][0];
        float* orow = out + (size_t)(row0 + r) * NG;
#pragma unroll
        for (int k = 0; k < GPT; ++k) {
            const int jb = (t3 + k * 1536) & (DIN - 1);
            float e1 = Lr[jb + 1];
            float e2 = Lr[jb + 2];
            float e3 = Lr[jb + 3];
            float o = fmaf(wq[k].x, e1,
                      fmaf(wq[k].y, e2,
                      fmaf(wq[k].z, e3, wq[k].w)));
            __builtin_nontemporal_store(o, orow + tid + (k << 9));
        }
    }
}

extern "C" void kernel_launch(void* const* d_in, const int* in_sizes, int n_in,
                              void* d_out, int out_size, void* d_ws, size_t ws_size,
                              hipStream_t stream) {
    const float* x    = (const float*)d_in[0];   // (BS, DIN) fp32
    const float* wgts = (const float*)d_in[1];   // (NG, 3, 4) fp32
    // d_in[2] (connections) is deterministic: (3g+1+j) % DIN — computed inline.
    float* out = (float*)d_out;                  // (BS, NG) fp32

    fredkin_rows<<<dim3(BS / R), dim3(BT), 0, stream>>>(x, wgts, out);
}